// Round 12
// baseline (855.887 us; speedup 1.0000x reference)
//
#include <hip/hip_runtime.h>
#include <math.h>

// Problem constants
#define B_  4096
#define L_  60
#define I_  13
#define H_  128
#define AHP 136            // h-tile pitch in halfs (272B rows: 16B-aligned, bank-spread)

typedef _Float16 half8 __attribute__((ext_vector_type(8)));
typedef _Float16 half4v __attribute__((ext_vector_type(4)));
typedef float float4v __attribute__((ext_vector_type(4)));

// ---------------------------------------------------------------------------
// Weight packing: B-fragment order for mfma_f32_16x16x32_f16.
// frag(kt, w4, ct), lane l, elem j ->
//   B[k = kt*32 + (l>>4)*8 + j][n = (ct>>1)*128 + w4*32 + (ct&1)*16 + (l&15)]
// linear e = (((kt*4 + w4)*8 + ct)*64 + l)*8 + j;  src [512][Ksrc] fp32.
// (Validated R3: absmax 7.8e-3.)
// ---------------------------------------------------------------------------
__global__ void pack_kernel(const float* __restrict__ src, _Float16* __restrict__ dst,
                            int Ksrc, int n,
                            const float* __restrict__ bih, const float* __restrict__ bhh,
                            float* __restrict__ bias_out) {
    int g0 = blockIdx.x * blockDim.x + threadIdx.x;
    for (int e = g0; e < n; e += gridDim.x * blockDim.x) {
        int j  = e & 7;
        int l  = (e >> 3) & 63;
        int ct = (e >> 9) & 7;
        int w4 = (e >> 12) & 3;
        int kt = e >> 14;
        int nn = (ct >> 1) * 128 + w4 * 32 + (ct & 1) * 16 + (l & 15);
        int k  = kt * 32 + ((l >> 4) << 3) + j;
        dst[e] = (k < Ksrc) ? (_Float16)src[nn * Ksrc + k] : (_Float16)0.f;
    }
    if (bias_out && g0 < 512) bias_out[g0] = bih[g0] + bhh[g0];
}

// Fast pointwise: v_rcp_f32 (~1 ulp; absmax budget 7.8e-3 — verified R6/R8/R12).
__device__ __forceinline__ float sigm(float x) {
    return __builtin_amdgcn_rcpf(1.f + __expf(-x));
}
__device__ __forceinline__ float tanh_f(float x) {
    return 1.f - 2.f * __builtin_amdgcn_rcpf(__expf(2.f * x) + 1.f);
}

// LDS carve (halfs), static — R15: W_hh is NO LONGER LDS-resident (streamed
// from the L2-hot pack with identical indexing: each wave's slice is a
// disjoint 16KB). This frees 128KB -> BOTH AH and XS double-buffer ->
// ONE barrier/step (R8-proven sync pattern).
//   AH0/AH1: 2 x 32 x AHP  (8704)
//   XS:      2 x 8192      (16384)   [L1/2; L0 uses 2 x 1024 of it as AX]
#define SMEM_HALFS (2 * 32 * AHP + 2 * 8192)   // 25088 halfs = 50176 B

// ---------------------------------------------------------------------------
// Persistent BiLSTM layer, MFMA f16.
// R15 theory: R13's pipe-sum (LDS 3.8k + L2 2.7k + MFMA 0.9k + trans 1.3k +
// barriers) ~= the observed 8.8k cyc/step -> the 2-barrier bulk-synchronous
// schedule serializes the pipes; the bottleneck is coupling, not one pipe.
// Fix: 1 barrier/step (all-dbuf LDS) so waves skew and pipes overlap; W_hh
// B-frags stream from L2 (same pack offsets, global pointer) — pack is read
// by all 32 blocks/XCD every step -> permanently L2-resident.
// Register cap 128 immovable (R4-R10) — FETCH is the spill tripwire.
// Wave (w4 = w&3, u = w>>2): w4 owns n-cols [w4*32,+32), u picks the 16-col
// half; wave computes real ct = tq*2+u for tq = 0..3. C/D frag:
// row=(lane>>4)*4+reg, col=lane&15. A/B frag: dim16=lane&15, k=(lane>>4)*8+j.
// ---------------------------------------------------------------------------
template <int XT, int IS_L0>
__global__ __launch_bounds__(512)
void lstm_mfma(const float* __restrict__ x0, const _Float16* __restrict__ yin,
               const _Float16* __restrict__ px_f, const _Float16* __restrict__ ph_f,
               const _Float16* __restrict__ px_b, const _Float16* __restrict__ ph_b,
               const float* __restrict__ bias_f, const float* __restrict__ bias_b,
               _Float16* __restrict__ yout)
{
    __shared__ _Float16 sm[SMEM_HALFS];
    _Float16* AH0 = sm;                        // 32 x AHP (h-tile, buffer 0)
    _Float16* AH1 = sm + 32 * AHP;             // 32 x AHP (h-tile, buffer 1)
    _Float16* XSb = sm + 2 * 32 * AHP;         // L1/2: 2 x 8192; L0: 2 x 1024 (AX)

    const int tid  = threadIdx.x;
    const int lane = tid & 63;
    const int w    = tid >> 6;      // 0..7
    const int w4   = w & 3;
    const int u    = w >> 2;        // 0/1: 16-col half within the 32-col block
    const int dir  = blockIdx.x & 1;
    const int rb   = (blockIdx.x >> 1) * 32;
    const int m    = lane & 15;
    const int q    = lane >> 4;
    const int jc   = w4 * 32 + u * 16 + m;     // this thread's h-column

    // Coalesced AH->yout copy mapping: thread owns 16B: row=tid>>4, colgrp=tid&15.
    const int crow = tid >> 4;
    const int ccg  = tid & 15;
    _Float16* __restrict__ ybase =
        yout + (size_t)(rb + crow) * 15360 + dir * H_ + ccg * 8;

    const _Float16* __restrict__ px   = dir ? px_b : px_f;
    const _Float16* __restrict__ ph   = dir ? ph_b : ph_f;
    const float*    __restrict__ bias = dir ? bias_b : bias_f;
    const _Float16* __restrict__ pWl  = px + w4 * 4096 + u * 512 + lane * 8;
    // W_hh B-frag base: GLOBAL (L2-hot pack), identical offsets to the old
    // LDS-resident WHl (the pack layout is what we used to memcpy into LDS).
    const _Float16* __restrict__ WHl  = ph + w4 * 4096 + u * 512 + lane * 8;

    // Zero both h-tile buffers (h(-1) = 0).
    for (int i = tid; i < 2 * 32 * AHP; i += 512) AH0[i] = (_Float16)0.f;

    float bv[4];
#pragma unroll
    for (int tq = 0; tq < 4; ++tq) bv[tq] = bias[tq * 128 + jc];

    if (IS_L0) {
        // ---------------- L0: dbuf AH + dbuf AX, 1 barrier/step (R8 pattern) ----------------
        _Float16* AX = XSb;                    // 2 x 1024 (dbuf)

        half8 bX[4];
#pragma unroll
        for (int tq = 0; tq < 4; ++tq) bX[tq] = *(const half8*)(pWl + tq * 1024);

        float cst[2][4];
#pragma unroll
        for (int rt = 0; rt < 2; ++rt)
#pragma unroll
            for (int r = 0; r < 4; ++r) cst[rt][r] = 0.f;

        for (int s = 0; s < L_; ++s) {
            const int t = dir ? (L_ - 1 - s) : s;
            _Float16* __restrict__ Hprev = (s & 1) ? AH0 : AH1;
            _Float16* __restrict__ Hcur  = (s & 1) ? AH1 : AH0;
            _Float16* __restrict__ AXs   = AX + (s & 1) * 1024;

            if (tid < 256) {
                const int e  = tid * 4;
                const int j0 = e & 7;
                const int ln = (e >> 3) & 63;
                const int rt = e >> 9;
                const int row = rt * 16 + (ln & 15);
                const int kb  = ((ln >> 4) << 3) + j0;
                const float* xr = x0 + (size_t)(rb + row) * (L_ * I_) + t * I_;
                half4v tmp;
#pragma unroll
                for (int jj = 0; jj < 4; ++jj) {
                    int k = kb + jj;
                    tmp[jj] = (k < I_) ? (_Float16)xr[k] : (_Float16)0.f;
                }
                ((half4v*)AXs)[tid] = tmp;
            }

            __syncthreads();   // AXs + h(s-1) visible; old-buffer reads done

            // deferred coalesced yout copy for step s-1 (h(s-1) lives in Hprev)
            if (s > 0) {
                const int tp = dir ? (t + 1) : (t - 1);
                half8 hv = *(const half8*)(Hprev + crow * AHP + ccg * 8);
                *(half8*)(ybase + tp * 256) = hv;
            }

            float4v acc[2][4];
#pragma unroll
            for (int rt = 0; rt < 2; ++rt)
#pragma unroll
                for (int tq = 0; tq < 4; ++tq) {
                    float b = bv[tq];
                    acc[rt][tq] = (float4v){b, b, b, b};
                }

            {
                half8 a0 = *(const half8*)(AXs + lane * 8);
                half8 a1 = *(const half8*)(AXs + 512 + lane * 8);
#pragma unroll
                for (int tq = 0; tq < 4; ++tq) {
                    acc[0][tq] = __builtin_amdgcn_mfma_f32_16x16x32_f16(a0, bX[tq], acc[0][tq], 0, 0, 0);
                    acc[1][tq] = __builtin_amdgcn_mfma_f32_16x16x32_f16(a1, bX[tq], acc[1][tq], 0, 0, 0);
                }
            }

#pragma unroll
            for (int kh = 0; kh < 4; ++kh) {
                half8 a0 = *(const half8*)(Hprev + m * AHP + kh * 32 + q * 8);
                half8 a1 = *(const half8*)(Hprev + (16 + m) * AHP + kh * 32 + q * 8);
#pragma unroll
                for (int tq = 0; tq < 4; ++tq) {
                    half8 b = *(const half8*)(WHl + kh * 16384 + tq * 1024);   // L2 stream
                    acc[0][tq] = __builtin_amdgcn_mfma_f32_16x16x32_f16(a0, b, acc[0][tq], 0, 0, 0);
                    acc[1][tq] = __builtin_amdgcn_mfma_f32_16x16x32_f16(a1, b, acc[1][tq], 0, 0, 0);
                }
            }

#pragma unroll
            for (int rt = 0; rt < 2; ++rt)
#pragma unroll
                for (int r = 0; r < 4; ++r) {
                    const float gi = acc[rt][0][r];
                    const float gf = acc[rt][1][r];
                    const float gg = acc[rt][2][r];
                    const float go = acc[rt][3][r];
                    const float cc = sigm(gf) * cst[rt][r] + sigm(gi) * tanh_f(gg);
                    cst[rt][r] = cc;
                    const float hh = sigm(go) * tanh_f(cc);
                    const int row = rt * 16 + q * 4 + r;
                    Hcur[row * AHP + jc] = (_Float16)hh;
                }
        }
        // epilogue: copy h(L-1)
        __syncthreads();
        {
            _Float16* __restrict__ Hl = ((L_ - 1) & 1) ? AH1 : AH0;
            const int tp = dir ? 0 : (L_ - 1);
            half8 hv = *(const half8*)(Hl + crow * AHP + ccg * 8);
            *(half8*)(ybase + tp * 256) = hv;
        }
        return;
    }

    // ---------------- L1/2: dbuf AH + dbuf XS, 1 barrier/step ----------------
    // Staging-chunk invariants: thread owns 16B chunks c0=2*tid, c0+1.
    // chunk c -> frag f=c>>6 (kt=f>>1, rt=f&1), lane-slot l=c&63:
    //   XS[f*512 + l*8 + j] = yin[(rb + rt*16 + (l&15)) * 15360 + t*256 + kt*32 + (l>>4)*8 + j]
    const int c0 = tid * 2;
    const int f0 = c0 >> 6,       l0 = c0 & 63;
    const int f1 = (c0 + 1) >> 6, l1 = (c0 + 1) & 63;
    const _Float16* __restrict__ sb0 =
        yin + (size_t)(rb + (f0 & 1) * 16 + (l0 & 15)) * 15360 + (f0 >> 1) * 32 + (l0 >> 4) * 8;
    const _Float16* __restrict__ sb1 =
        yin + (size_t)(rb + (f1 & 1) * 16 + (l1 & 15)) * 15360 + (f1 >> 1) * 32 + (l1 >> 4) * 8;

    // Prologue: stage x(s=0) into XS buffer 0.
    {
        const int t0 = dir ? (L_ - 1) : 0;
        _Float16* xw = XSb + c0 * 8;
        *(half8*)xw       = *(const half8*)(sb0 + t0 * 256);
        *(half8*)(xw + 8) = *(const half8*)(sb1 + t0 * 256);
    }

    float cst[2][4];
#pragma unroll
    for (int rt = 0; rt < 2; ++rt)
#pragma unroll
        for (int r = 0; r < 4; ++r) cst[rt][r] = 0.f;

    __syncthreads();   // AH zeros + XS(0) visible

    for (int s = 0; s < L_; ++s) {
        const int t  = dir ? (L_ - 1 - s) : s;
        const int sn = (s + 1 < L_) ? s + 1 : s;          // clamp (last stage unused)
        const int tn = dir ? (L_ - 1 - sn) : sn;
        _Float16* __restrict__ Hprev = (s & 1) ? AH0 : AH1;   // written at s-1
        _Float16* __restrict__ Hcur  = (s & 1) ? AH1 : AH0;
        const _Float16* __restrict__ XSs = XSb + (s & 1) * 8192;
        _Float16* __restrict__ XSn = XSb + ((s + 1) & 1) * 8192;

        // issue next-step staging loads (full-step prefetch distance)
        half8 sg0 = *(const half8*)(sb0 + tn * 256);
        half8 sg1 = *(const half8*)(sb1 + tn * 256);

        // deferred coalesced yout copy for step s-1 (h(s-1) lives in Hprev);
        // store latency hides under the MFMA phase.
        if (s > 0) {
            const int tp = dir ? (t + 1) : (t - 1);
            half8 hv = *(const half8*)(Hprev + crow * AHP + ccg * 8);
            *(half8*)(ybase + tp * 256) = hv;
        }

        half8 bC[4], bN[4];
#pragma unroll
        for (int tq = 0; tq < 4; ++tq) bC[tq] = *(const half8*)(pWl + tq * 1024);

        float4v acc[2][4];
#pragma unroll
        for (int rt = 0; rt < 2; ++rt)
#pragma unroll
            for (int tq = 0; tq < 4; ++tq) {
                float b = bv[tq];
                acc[rt][tq] = (float4v){b, b, b, b};
            }

        // kt loop; h-block at EVEN kt (kh=kt>>1, all 4 tq; hA read once);
        // h-B streamed from L2 (WHl global). x-B 1-deep prefetched.
#pragma unroll
        for (int kt = 0; kt < XT; ++kt) {
            if (kt + 1 < XT) {
#pragma unroll
                for (int tq = 0; tq < 4; ++tq)
                    bN[tq] = *(const half8*)(pWl + (kt + 1) * 16384 + tq * 1024);
            }
            if ((kt & 1) == 0) {
                const int kh = kt >> 1;
                half8 ha0 = *(const half8*)(Hprev + m * AHP + kh * 32 + q * 8);
                half8 ha1 = *(const half8*)(Hprev + (16 + m) * AHP + kh * 32 + q * 8);
#pragma unroll
                for (int tq = 0; tq < 4; ++tq) {
                    half8 hb = *(const half8*)(WHl + kh * 16384 + tq * 1024);  // L2 stream
                    acc[0][tq] = __builtin_amdgcn_mfma_f32_16x16x32_f16(ha0, hb, acc[0][tq], 0, 0, 0);
                    acc[1][tq] = __builtin_amdgcn_mfma_f32_16x16x32_f16(ha1, hb, acc[1][tq], 0, 0, 0);
                }
            }
            half8 a0 = *(const half8*)(XSs + (kt * 2 + 0) * 512 + lane * 8);
            half8 a1 = *(const half8*)(XSs + (kt * 2 + 1) * 512 + lane * 8);
#pragma unroll
            for (int tq = 0; tq < 4; ++tq) {
                acc[0][tq] = __builtin_amdgcn_mfma_f32_16x16x32_f16(a0, bC[tq], acc[0][tq], 0, 0, 0);
                acc[1][tq] = __builtin_amdgcn_mfma_f32_16x16x32_f16(a1, bC[tq], acc[1][tq], 0, 0, 0);
            }
            if (kt + 1 < XT) {
#pragma unroll
                for (int tq = 0; tq < 4; ++tq) bC[tq] = bN[tq];
            }
        }

        // pointwise -> h(s); write XS(s+1) and AH(s); single barrier ends the step
        *(half8*)(XSn + c0 * 8)     = sg0;
        *(half8*)(XSn + c0 * 8 + 8) = sg1;
#pragma unroll
        for (int rt = 0; rt < 2; ++rt)
#pragma unroll
            for (int r = 0; r < 4; ++r) {
                const float gi = acc[rt][0][r];
                const float gf = acc[rt][1][r];
                const float gg = acc[rt][2][r];
                const float go = acc[rt][3][r];
                const float cc = sigm(gf) * cst[rt][r] + sigm(gi) * tanh_f(gg);
                cst[rt][r] = cc;
                const float hh = sigm(go) * tanh_f(cc);
                const int row = rt * 16 + q * 4 + r;
                Hcur[row * AHP + jc] = (_Float16)hh;
            }

        __syncthreads();   // XS(s+1) + AH(s) visible; XSs/Hprev reads done
    }

    // epilogue: copy h(L-1)
    {
        _Float16* __restrict__ Hl = ((L_ - 1) & 1) ? AH1 : AH0;
        const int tp = dir ? 0 : (L_ - 1);
        half8 hv = *(const half8*)(Hl + crow * AHP + ccg * 8);
        *(half8*)(ybase + tp * 256) = hv;
    }
}

// ---------------------------------------------------------------------------
// Final: out[b][o] = b_out[o] + sum relu(y3[b][:]) * w_out[o][:]
// ---------------------------------------------------------------------------
__global__ __launch_bounds__(256)
void final_kernel(const _Float16* __restrict__ y, const float* __restrict__ wout,
                  const float* __restrict__ bout, float* __restrict__ outp, int nrows) {
    const int wid  = (blockIdx.x * blockDim.x + threadIdx.x) >> 6;
    const int lane = threadIdx.x & 63;
    if (wid >= nrows) return;
    const half8*  __restrict__ y8 = (const half8*)(y + (size_t)wid * 15360);
    const float4* __restrict__ w4 = (const float4*)wout;   // [2][3840]
    float s0 = 0.f, s1 = 0.f;
#pragma unroll 2
    for (int it = 0; it < 30; ++it) {
        const int idx = it * 64 + lane;
        half8 h = y8[idx];
        float v[8];
#pragma unroll
        for (int e = 0; e < 8; ++e) v[e] = fmaxf((float)h[e], 0.f);
        const float4 a0 = w4[idx * 2], a1 = w4[idx * 2 + 1];
        const float4 b0 = w4[3840 + idx * 2], b1 = w4[3840 + idx * 2 + 1];
        s0 += v[0] * a0.x + v[1] * a0.y + v[2] * a0.z + v[3] * a0.w
            + v[4] * a1.x + v[5] * a1.y + v[6] * a1.z + v[7] * a1.w;
        s1 += v[0] * b0.x + v[1] * b0.y + v[2] * b0.z + v[3] * b0.w
            + v[4] * b1.x + v[5] * b1.y + v[6] * b1.z + v[7] * b1.w;
    }
#pragma unroll
    for (int off = 32; off > 0; off >>= 1) {
        s0 += __shfl_down(s0, off);
        s1 += __shfl_down(s1, off);
    }
    if (lane == 0) {
        outp[wid * 2 + 0] = s0 + bout[0];
        outp[wid * 2 + 1] = s1 + bout[1];
    }
}

// ---------------------------------------------------------------------------
extern "C" void kernel_launch(void* const* d_in, const int* in_sizes, int n_in,
                              void* d_out, int out_size, void* d_ws, size_t ws_size,
                              hipStream_t stream) {
    const float* x = (const float*)d_in[0];
    auto W = [&](int l, int d, int which) { return (const float*)d_in[1 + l * 8 + d * 4 + which]; };
    const float* w_out = (const float*)d_in[25];
    const float* b_out = (const float*)d_in[26];

    // Workspace: packs (halfs) -> fp32 bias -> fp16 y ping-pong buffers.
    _Float16* wsH = (_Float16*)d_ws;
    const size_t px0f = 0,       ph0f = 16384;
    const size_t px0b = 81920,   ph0b = 98304;
    const size_t px1f = 163840,  ph1f = 294912;
    const size_t px1b = 360448,  ph1b = 491520;
    const size_t px2f = 557056,  ph2f = 688128;
    const size_t px2b = 753664,  ph2b = 884736;
    const size_t packs_end = 950272;
    float* bias = (float*)(wsH + packs_end);      // 6*512 fp32
    const size_t head_bytes = packs_end * 2 + 4096 * 4;
    _Float16* y0 = (_Float16*)((char*)d_ws + head_bytes);

    // ---- weight packing (+ bias combine on the px launches) ----
    pack_kernel<<<64, 256, 0, stream>>>(W(0,0,0), wsH + px0f, I_,  16384,  W(0,0,2), W(0,0,3), bias + 0);
    pack_kernel<<<256,256, 0, stream>>>(W(0,0,1), wsH + ph0f, H_,  65536,  nullptr, nullptr, nullptr);
    pack_kernel<<<64, 256, 0, stream>>>(W(0,1,0), wsH + px0b, I_,  16384,  W(0,1,2), W(0,1,3), bias + 512);
    pack_kernel<<<256,256, 0, stream>>>(W(0,1,1), wsH + ph0b, H_,  65536,  nullptr, nullptr, nullptr);
    pack_kernel<<<512,256, 0, stream>>>(W(1,0,0), wsH + px1f, 256, 131072, W(1,0,2), W(1,0,3), bias + 1024);
    pack_kernel<<<256,256, 0, stream>>>(W(1,0,1), wsH + ph1f, H_,  65536,  nullptr, nullptr, nullptr);
    pack_kernel<<<512,256, 0, stream>>>(W(1,1,0), wsH + px1b, 256, 131072, W(1,1,2), W(1,1,3), bias + 1536);
    pack_kernel<<<256,256, 0, stream>>>(W(1,1,1), wsH + ph1b, H_,  65536,  nullptr, nullptr, nullptr);
    pack_kernel<<<512,256, 0, stream>>>(W(2,0,0), wsH + px2f, 256, 131072, W(2,0,2), W(2,0,3), bias + 2048);
    pack_kernel<<<256,256, 0, stream>>>(W(2,0,1), wsH + ph2f, H_,  65536,  nullptr, nullptr, nullptr);
    pack_kernel<<<512,256, 0, stream>>>(W(2,1,0), wsH + px2b, 256, 131072, W(2,1,2), W(2,1,3), bias + 2560);
    pack_kernel<<<256,256, 0, stream>>>(W(2,1,1), wsH + ph2b, H_,  65536,  nullptr, nullptr, nullptr);

    // ---- pick batch chunking so 2 fp16 y-buffers fit in remaining ws ----
    const size_t avail_halfs = (ws_size > head_bytes) ? (ws_size - head_bytes) / 2 : 0;
    int chunks = 1;
    while (chunks < 128 && (size_t)2 * (B_ / chunks) * 15360 > avail_halfs) chunks *= 2;
    const int CB = B_ / chunks;              // multiple of 32

    _Float16* yA = y0;
    _Float16* yB = y0 + (size_t)CB * 15360;

    for (int c = 0; c < chunks; ++c) {
        const float* xc = x + (size_t)c * CB * (L_ * I_);
        float* outc = (float*)d_out + (size_t)c * CB * 2;
        lstm_mfma<1, 1><<<2 * CB / 32, 512, 0, stream>>>(
            xc, nullptr, wsH + px0f, wsH + ph0f, wsH + px0b, wsH + ph0b, bias + 0, bias + 512, yA);
        lstm_mfma<8, 0><<<2 * CB / 32, 512, 0, stream>>>(
            nullptr, yA, wsH + px1f, wsH + ph1f, wsH + px1b, wsH + ph1b, bias + 1024, bias + 1536, yB);
        lstm_mfma<8, 0><<<2 * CB / 32, 512, 0, stream>>>(
            nullptr, yB, wsH + px2f, wsH + ph2f, wsH + px2b, wsH + ph2b, bias + 2048, bias + 2560, yA);
        final_kernel<<<(CB + 3) / 4, 256, 0, stream>>>(yA, w_out, b_out, outc, CB);
    }
}

// Round 13
// 650.129 us; speedup vs baseline: 1.3165x; 1.3165x over previous
//
#include <hip/hip_runtime.h>
#include <math.h>

// Problem constants
#define B_  4096
#define L_  60
#define I_  13
#define H_  128
#define AHP 136            // h-tile pitch in halfs (272B rows: 16B-aligned)

typedef _Float16 half8 __attribute__((ext_vector_type(8)));
typedef _Float16 half4v __attribute__((ext_vector_type(4)));
typedef float float4v __attribute__((ext_vector_type(4)));

// ---------------------------------------------------------------------------
// Weight packing: B-fragment order for mfma_f32_16x16x32_f16.
// frag(kt, w4, ct), lane l, elem j ->
//   B[k = kt*32 + (l>>4)*8 + j][n = (ct>>1)*128 + w4*32 + (ct&1)*16 + (l&15)]
// linear e = (((kt*4 + w4)*8 + ct)*64 + l)*8 + j;  src [512][Ksrc] fp32.
// (Validated R3: absmax 7.8e-3.)
// ---------------------------------------------------------------------------
__global__ void pack_kernel(const float* __restrict__ src, _Float16* __restrict__ dst,
                            int Ksrc, int n,
                            const float* __restrict__ bih, const float* __restrict__ bhh,
                            float* __restrict__ bias_out) {
    int g0 = blockIdx.x * blockDim.x + threadIdx.x;
    for (int e = g0; e < n; e += gridDim.x * blockDim.x) {
        int j  = e & 7;
        int l  = (e >> 3) & 63;
        int ct = (e >> 9) & 7;
        int w4 = (e >> 12) & 3;
        int kt = e >> 14;
        int nn = (ct >> 1) * 128 + w4 * 32 + (ct & 1) * 16 + (l & 15);
        int k  = kt * 32 + ((l >> 4) << 3) + j;
        dst[e] = (k < Ksrc) ? (_Float16)src[nn * Ksrc + k] : (_Float16)0.f;
    }
    if (bias_out && g0 < 512) bias_out[g0] = bih[g0] + bhh[g0];
}

// Fast pointwise: v_rcp_f32 (~1 ulp; absmax budget 7.8e-3 — verified R6/R8/R12).
__device__ __forceinline__ float sigm(float x) {
    return __builtin_amdgcn_rcpf(1.f + __expf(-x));
}
__device__ __forceinline__ float tanh_f(float x) {
    return 1.f - 2.f * __builtin_amdgcn_rcpf(__expf(2.f * x) + 1.f);
}

// LDS carve (halfs), static:
//   WH [0, 65536)                                  128 KB  (both paths)
//   L0 path:    AH0/AH1 dbuf 2 x 32 x AHP, AX dbuf 2 x 1024   -> 76288 total
//   L1/2 path:  AH single 32 x AHP, XS x-stage 16 x 512        -> 78080 total
#define SMEM_HALFS 78080   // 156160 B <= 160 KB -> 1 block/CU

// ---------------------------------------------------------------------------
// Persistent BiLSTM layer, MFMA f16.  SESSION-BEST STRUCTURE (R13, verified
// 650.8us total / 219.4us per L1-2 dispatch / MfmaUtil 39.7% / clean FETCH):
//  - XS full-step-prefetch staging of the yin A-tile (R12: removed the ~7k
//    cyc/step exposed yin latency that dominated R8).
//  - DEFERRED COALESCED YOUT (R13): phase 2 writes AH only; the yout copy for
//    step s-1 runs at the top of step s's MFMA phase (1 ds_read_b128 + 1
//    dwordx4 store/thread, coalesced) so store drain overlaps compute.
//  - H-INTERLEAVE (R13): 4 h-MFMAs per kt (kh=kt>>1, tq-pair=kt&1) keep the
//    matrix pipe fed across the B-prefetch latency.
// REFUTED ALTERNATIVES (do not revisit): TC>1 acc blocking (R4-R7: 128-VGPR
// cap immovable across 5 launch-bounds/waves_per_eu/static-LDS spellings ->
// scratch spill); 16-wave blocks (R9: cap halves to 64); pointwise hoist +
// hA dedup (R14: neutral-negative, conflicts unchanged); W_hh streamed from
// L2 for 1-barrier all-dbuf schedule (R15: -50%, h-B latency exposure; LDS
// over budget for the WH-resident variant).
// Wave (w4 = w&3, u = w>>2): w4 owns n-cols [w4*32,+32), u picks the 16-col
// half; wave computes real ct = tq*2+u for tq = 0..3. C/D frag:
// row=(lane>>4)*4+reg, col=lane&15. A/B frag: dim16=lane&15, k=(lane>>4)*8+j.
// ---------------------------------------------------------------------------
template <int XT, int IS_L0>
__global__ __launch_bounds__(512)
void lstm_mfma(const float* __restrict__ x0, const _Float16* __restrict__ yin,
               const _Float16* __restrict__ px_f, const _Float16* __restrict__ ph_f,
               const _Float16* __restrict__ px_b, const _Float16* __restrict__ ph_b,
               const float* __restrict__ bias_f, const float* __restrict__ bias_b,
               _Float16* __restrict__ yout)
{
    __shared__ _Float16 sm[SMEM_HALFS];
    _Float16* WH = sm;                         // 65536 halfs (128 KB)

    const int tid  = threadIdx.x;
    const int lane = tid & 63;
    const int w    = tid >> 6;      // 0..7
    const int w4   = w & 3;
    const int u    = w >> 2;        // 0/1: 16-col half within the 32-col block
    const int dir  = blockIdx.x & 1;
    const int rb   = (blockIdx.x >> 1) * 32;
    const int m    = lane & 15;
    const int q    = lane >> 4;
    const int jc   = w4 * 32 + u * 16 + m;     // this thread's h-column

    // Coalesced AH->yout copy mapping: thread owns 16B: row=tid>>4, colgrp=tid&15.
    const int crow = tid >> 4;
    const int ccg  = tid & 15;
    _Float16* __restrict__ ybase =
        yout + (size_t)(rb + crow) * 15360 + dir * H_ + ccg * 8;

    const _Float16* __restrict__ px   = dir ? px_b : px_f;
    const _Float16* __restrict__ ph   = dir ? ph_b : ph_f;
    const float*    __restrict__ bias = dir ? bias_b : bias_f;
    const _Float16* __restrict__ pWl  = px + w4 * 4096 + u * 512 + lane * 8;
    const _Float16* __restrict__ WHl  = WH + w4 * 4096 + u * 512 + lane * 8;

    // Load W_hh pack into LDS.
    {
        const half8* s8 = (const half8*)ph;
        half8* d8 = (half8*)WH;
        for (int i = tid; i < 8192; i += 512) d8[i] = s8[i];
    }

    float bv[4];
#pragma unroll
    for (int tq = 0; tq < 4; ++tq) bv[tq] = bias[tq * 128 + jc];

    if (IS_L0) {
        // ---------------- L0: R8 structure + deferred coalesced yout ----------------
        _Float16* AH0 = sm + 65536;            // 32 x AHP
        _Float16* AH1 = AH0 + 32 * AHP;
        _Float16* AX  = AH1 + 32 * AHP;        // 2 x 1024 (dbuf)
        for (int i = tid; i < 2 * 32 * AHP; i += 512) AH0[i] = (_Float16)0.f;

        half8 bX[4];
#pragma unroll
        for (int tq = 0; tq < 4; ++tq) bX[tq] = *(const half8*)(pWl + tq * 1024);

        float cst[2][4];
#pragma unroll
        for (int rt = 0; rt < 2; ++rt)
#pragma unroll
            for (int r = 0; r < 4; ++r) cst[rt][r] = 0.f;

        for (int s = 0; s < L_; ++s) {
            const int t = dir ? (L_ - 1 - s) : s;
            _Float16* __restrict__ Hprev = (s & 1) ? AH0 : AH1;
            _Float16* __restrict__ Hcur  = (s & 1) ? AH1 : AH0;
            _Float16* __restrict__ AXs   = AX + (s & 1) * 1024;

            if (tid < 256) {
                const int e  = tid * 4;
                const int j0 = e & 7;
                const int ln = (e >> 3) & 63;
                const int rt = e >> 9;
                const int row = rt * 16 + (ln & 15);
                const int kb  = ((ln >> 4) << 3) + j0;
                const float* xr = x0 + (size_t)(rb + row) * (L_ * I_) + t * I_;
                half4v tmp;
#pragma unroll
                for (int jj = 0; jj < 4; ++jj) {
                    int k = kb + jj;
                    tmp[jj] = (k < I_) ? (_Float16)xr[k] : (_Float16)0.f;
                }
                ((half4v*)AXs)[tid] = tmp;
            }

            __syncthreads();

            // deferred coalesced yout copy for step s-1 (h(s-1) lives in Hprev)
            if (s > 0) {
                const int tp = dir ? (t + 1) : (t - 1);
                half8 hv = *(const half8*)(Hprev + crow * AHP + ccg * 8);
                *(half8*)(ybase + tp * 256) = hv;
            }

            float4v acc[2][4];
#pragma unroll
            for (int rt = 0; rt < 2; ++rt)
#pragma unroll
                for (int tq = 0; tq < 4; ++tq) {
                    float b = bv[tq];
                    acc[rt][tq] = (float4v){b, b, b, b};
                }

            {
                half8 a0 = *(const half8*)(AXs + lane * 8);
                half8 a1 = *(const half8*)(AXs + 512 + lane * 8);
#pragma unroll
                for (int tq = 0; tq < 4; ++tq) {
                    acc[0][tq] = __builtin_amdgcn_mfma_f32_16x16x32_f16(a0, bX[tq], acc[0][tq], 0, 0, 0);
                    acc[1][tq] = __builtin_amdgcn_mfma_f32_16x16x32_f16(a1, bX[tq], acc[1][tq], 0, 0, 0);
                }
            }

#pragma unroll
            for (int kh = 0; kh < 4; ++kh) {
                half8 a0 = *(const half8*)(Hprev + m * AHP + kh * 32 + q * 8);
                half8 a1 = *(const half8*)(Hprev + (16 + m) * AHP + kh * 32 + q * 8);
#pragma unroll
                for (int tq = 0; tq < 4; ++tq) {
                    half8 b = *(const half8*)(WHl + kh * 16384 + tq * 1024);
                    acc[0][tq] = __builtin_amdgcn_mfma_f32_16x16x32_f16(a0, b, acc[0][tq], 0, 0, 0);
                    acc[1][tq] = __builtin_amdgcn_mfma_f32_16x16x32_f16(a1, b, acc[1][tq], 0, 0, 0);
                }
            }

#pragma unroll
            for (int rt = 0; rt < 2; ++rt)
#pragma unroll
                for (int r = 0; r < 4; ++r) {
                    const float gi = acc[rt][0][r];
                    const float gf = acc[rt][1][r];
                    const float gg = acc[rt][2][r];
                    const float go = acc[rt][3][r];
                    const float cc = sigm(gf) * cst[rt][r] + sigm(gi) * tanh_f(gg);
                    cst[rt][r] = cc;
                    const float hh = sigm(go) * tanh_f(cc);
                    const int row = rt * 16 + q * 4 + r;
                    Hcur[row * AHP + jc] = (_Float16)hh;
                }
        }
        // epilogue: copy h(L-1) (in Hcur of step L-1)
        __syncthreads();
        {
            _Float16* __restrict__ Hl = ((L_ - 1) & 1) ? AH1 : AH0;
            const int tp = dir ? 0 : (L_ - 1);
            half8 hv = *(const half8*)(Hl + crow * AHP + ccg * 8);
            *(half8*)(ybase + tp * 256) = hv;
        }
        return;
    }

    // ---------------- L1/2: XS-staged, h-interleaved, deferred-yout ----------------
    _Float16* AH = sm + 65536;                 // 32 x AHP (single)
    _Float16* XS = AH + 32 * AHP;              // 16 frags x 512 halfs (16 KB)
    for (int i = tid; i < 32 * AHP; i += 512) AH[i] = (_Float16)0.f;

    // Staging-chunk invariants: thread owns 16B chunks c0=2*tid, c0+1.
    // chunk c -> frag f=c>>6 (kt=f>>1, rt=f&1), lane-slot l=c&63:
    //   XS[f*512 + l*8 + j] = yin[(rb + rt*16 + (l&15)) * 15360 + t*256 + kt*32 + (l>>4)*8 + j]
    const int c0 = tid * 2;
    const int f0 = c0 >> 6,       l0 = c0 & 63;
    const int f1 = (c0 + 1) >> 6, l1 = (c0 + 1) & 63;
    const _Float16* __restrict__ sb0 =
        yin + (size_t)(rb + (f0 & 1) * 16 + (l0 & 15)) * 15360 + (f0 >> 1) * 32 + (l0 >> 4) * 8;
    const _Float16* __restrict__ sb1 =
        yin + (size_t)(rb + (f1 & 1) * 16 + (l1 & 15)) * 15360 + (f1 >> 1) * 32 + (l1 >> 4) * 8;
    _Float16* __restrict__ xw = XS + c0 * 8;

    // Prologue: stage x(s=0) directly.
    {
        const int t0 = dir ? (L_ - 1) : 0;
        *(half8*)xw       = *(const half8*)(sb0 + t0 * 256);
        *(half8*)(xw + 8) = *(const half8*)(sb1 + t0 * 256);
    }

    float cst[2][4];
#pragma unroll
    for (int rt = 0; rt < 2; ++rt)
#pragma unroll
        for (int r = 0; r < 4; ++r) cst[rt][r] = 0.f;

    __syncthreads();   // WH + AH zero + XS(0) visible

    for (int s = 0; s < L_; ++s) {
        const int t  = dir ? (L_ - 1 - s) : s;
        const int sn = (s + 1 < L_) ? s + 1 : s;          // clamp (last stage unused)
        const int tn = dir ? (L_ - 1 - sn) : sn;

        // ---- phase 1 ----
        half8 sg0 = *(const half8*)(sb0 + tn * 256);      // full-step prefetch distance
        half8 sg1 = *(const half8*)(sb1 + tn * 256);

        half8 bC[4], bN[4];
#pragma unroll
        for (int tq = 0; tq < 4; ++tq) bC[tq] = *(const half8*)(pWl + tq * 1024);

        // deferred coalesced yout copy for step s-1 (h(s-1) is in AH);
        // store latency hides under the MFMA phase below.
        if (s > 0) {
            const int tp = dir ? (t + 1) : (t - 1);
            half8 hv = *(const half8*)(AH + crow * AHP + ccg * 8);
            *(half8*)(ybase + tp * 256) = hv;
        }

        float4v acc[2][4];
#pragma unroll
        for (int rt = 0; rt < 2; ++rt)
#pragma unroll
            for (int tq = 0; tq < 4; ++tq) {
                float b = bv[tq];
                acc[rt][tq] = (float4v){b, b, b, b};
            }

        // kt loop with interleaved h-cover: per kt, 4 h-MFMAs (kh=kt>>1,
        // tq-pair=kt&1, pure LDS) + 8 x-MFMAs. B 1-deep prefetched.
#pragma unroll
        for (int kt = 0; kt < XT; ++kt) {
            if (kt + 1 < XT) {
#pragma unroll
                for (int tq = 0; tq < 4; ++tq)
                    bN[tq] = *(const half8*)(pWl + (kt + 1) * 16384 + tq * 1024);
            }
            {
                const int kh  = kt >> 1;
                const int tqb = (kt & 1) * 2;
                half8 ha0 = *(const half8*)(AH + m * AHP + kh * 32 + q * 8);
                half8 ha1 = *(const half8*)(AH + (16 + m) * AHP + kh * 32 + q * 8);
#pragma unroll
                for (int e = 0; e < 2; ++e) {
                    half8 hb = *(const half8*)(WHl + kh * 16384 + (tqb + e) * 1024);
                    acc[0][tqb + e] = __builtin_amdgcn_mfma_f32_16x16x32_f16(ha0, hb, acc[0][tqb + e], 0, 0, 0);
                    acc[1][tqb + e] = __builtin_amdgcn_mfma_f32_16x16x32_f16(ha1, hb, acc[1][tqb + e], 0, 0, 0);
                }
            }
            half8 a0 = *(const half8*)(XS + (kt * 2 + 0) * 512 + lane * 8);
            half8 a1 = *(const half8*)(XS + (kt * 2 + 1) * 512 + lane * 8);
#pragma unroll
            for (int tq = 0; tq < 4; ++tq) {
                acc[0][tq] = __builtin_amdgcn_mfma_f32_16x16x32_f16(a0, bC[tq], acc[0][tq], 0, 0, 0);
                acc[1][tq] = __builtin_amdgcn_mfma_f32_16x16x32_f16(a1, bC[tq], acc[1][tq], 0, 0, 0);
            }
            if (kt + 1 < XT) {
#pragma unroll
                for (int tq = 0; tq < 4; ++tq) bC[tq] = bN[tq];
            }
        }

        __syncthreads();   // barB: all XS/AH reads done

        // ---- phase 2: overwrite XS with x(s+1); pointwise writes AH only ----
        *(half8*)xw       = sg0;
        *(half8*)(xw + 8) = sg1;

#pragma unroll
        for (int rt = 0; rt < 2; ++rt)
#pragma unroll
            for (int r = 0; r < 4; ++r) {
                const float gi = acc[rt][0][r];
                const float gf = acc[rt][1][r];
                const float gg = acc[rt][2][r];
                const float go = acc[rt][3][r];
                const float cc = sigm(gf) * cst[rt][r] + sigm(gi) * tanh_f(gg);
                cst[rt][r] = cc;
                const float hh = sigm(go) * tanh_f(cc);
                const int row = rt * 16 + q * 4 + r;
                AH[row * AHP + jc] = (_Float16)hh;
            }

        __syncthreads();   // barA: XS(s+1) + AH(s) visible
    }

    // epilogue: copy h(L-1) (in AH)
    {
        const int tp = dir ? 0 : (L_ - 1);
        half8 hv = *(const half8*)(AH + crow * AHP + ccg * 8);
        *(half8*)(ybase + tp * 256) = hv;
    }
}

// ---------------------------------------------------------------------------
// Final: out[b][o] = b_out[o] + sum relu(y3[b][:]) * w_out[o][:]
// ---------------------------------------------------------------------------
__global__ __launch_bounds__(256)
void final_kernel(const _Float16* __restrict__ y, const float* __restrict__ wout,
                  const float* __restrict__ bout, float* __restrict__ outp, int nrows) {
    const int wid  = (blockIdx.x * blockDim.x + threadIdx.x) >> 6;
    const int lane = threadIdx.x & 63;
    if (wid >= nrows) return;
    const half8*  __restrict__ y8 = (const half8*)(y + (size_t)wid * 15360);
    const float4* __restrict__ w4 = (const float4*)wout;   // [2][3840]
    float s0 = 0.f, s1 = 0.f;
#pragma unroll 2
    for (int it = 0; it < 30; ++it) {
        const int idx = it * 64 + lane;
        half8 h = y8[idx];
        float v[8];
#pragma unroll
        for (int e = 0; e < 8; ++e) v[e] = fmaxf((float)h[e], 0.f);
        const float4 a0 = w4[idx * 2], a1 = w4[idx * 2 + 1];
        const float4 b0 = w4[3840 + idx * 2], b1 = w4[3840 + idx * 2 + 1];
        s0 += v[0] * a0.x + v[1] * a0.y + v[2] * a0.z + v[3] * a0.w
            + v[4] * a1.x + v[5] * a1.y + v[6] * a1.z + v[7] * a1.w;
        s1 += v[0] * b0.x + v[1] * b0.y + v[2] * b0.z + v[3] * b0.w
            + v[4] * b1.x + v[5] * b1.y + v[6] * b1.z + v[7] * b1.w;
    }
#pragma unroll
    for (int off = 32; off > 0; off >>= 1) {
        s0 += __shfl_down(s0, off);
        s1 += __shfl_down(s1, off);
    }
    if (lane == 0) {
        outp[wid * 2 + 0] = s0 + bout[0];
        outp[wid * 2 + 1] = s1 + bout[1];
    }
}

// ---------------------------------------------------------------------------
extern "C" void kernel_launch(void* const* d_in, const int* in_sizes, int n_in,
                              void* d_out, int out_size, void* d_ws, size_t ws_size,
                              hipStream_t stream) {
    const float* x = (const float*)d_in[0];
    auto W = [&](int l, int d, int which) { return (const float*)d_in[1 + l * 8 + d * 4 + which]; };
    const float* w_out = (const float*)d_in[25];
    const float* b_out = (const float*)d_in[26];

    // Workspace: packs (halfs) -> fp32 bias -> fp16 y ping-pong buffers.
    _Float16* wsH = (_Float16*)d_ws;
    const size_t px0f = 0,       ph0f = 16384;
    const size_t px0b = 81920,   ph0b = 98304;
    const size_t px1f = 163840,  ph1f = 294912;
    const size_t px1b = 360448,  ph1b = 491520;
    const size_t px2f = 557056,  ph2f = 688128;
    const size_t px2b = 753664,  ph2b = 884736;
    const size_t packs_end = 950272;
    float* bias = (float*)(wsH + packs_end);      // 6*512 fp32
    const size_t head_bytes = packs_end * 2 + 4096 * 4;
    _Float16* y0 = (_Float16*)((char*)d_ws + head_bytes);

    // ---- weight packing (+ bias combine on the px launches) ----
    pack_kernel<<<64, 256, 0, stream>>>(W(0,0,0), wsH + px0f, I_,  16384,  W(0,0,2), W(0,0,3), bias + 0);
    pack_kernel<<<256,256, 0, stream>>>(W(0,0,1), wsH + ph0f, H_,  65536,  nullptr, nullptr, nullptr);
    pack_kernel<<<64, 256, 0, stream>>>(W(0,1,0), wsH + px0b, I_,  16384,  W(0,1,2), W(0,1,3), bias + 512);
    pack_kernel<<<256,256, 0, stream>>>(W(0,1,1), wsH + ph0b, H_,  65536,  nullptr, nullptr, nullptr);
    pack_kernel<<<512,256, 0, stream>>>(W(1,0,0), wsH + px1f, 256, 131072, W(1,0,2), W(1,0,3), bias + 1024);
    pack_kernel<<<256,256, 0, stream>>>(W(1,0,1), wsH + ph1f, H_,  65536,  nullptr, nullptr, nullptr);
    pack_kernel<<<512,256, 0, stream>>>(W(1,1,0), wsH + px1b, 256, 131072, W(1,1,2), W(1,1,3), bias + 1536);
    pack_kernel<<<256,256, 0, stream>>>(W(1,1,1), wsH + ph1b, H_,  65536,  nullptr, nullptr, nullptr);
    pack_kernel<<<512,256, 0, stream>>>(W(2,0,0), wsH + px2f, 256, 131072, W(2,0,2), W(2,0,3), bias + 2048);
    pack_kernel<<<256,256, 0, stream>>>(W(2,0,1), wsH + ph2f, H_,  65536,  nullptr, nullptr, nullptr);
    pack_kernel<<<512,256, 0, stream>>>(W(2,1,0), wsH + px2b, 256, 131072, W(2,1,2), W(2,1,3), bias + 2560);
    pack_kernel<<<256,256, 0, stream>>>(W(2,1,1), wsH + ph2b, H_,  65536,  nullptr, nullptr, nullptr);

    // ---- pick batch chunking so 2 fp16 y-buffers fit in remaining ws ----
    const size_t avail_halfs = (ws_size > head_bytes) ? (ws_size - head_bytes) / 2 : 0;
    int chunks = 1;
    while (chunks < 128 && (size_t)2 * (B_ / chunks) * 15360 > avail_halfs) chunks *= 2;
    const int CB = B_ / chunks;              // multiple of 32

    _Float16* yA = y0;
    _Float16* yB = y0 + (size_t)CB * 15360;

    for (int c = 0; c < chunks; ++c) {
        const float* xc = x + (size_t)c * CB * (L_ * I_);
        float* outc = (float*)d_out + (size_t)c * CB * 2;
        lstm_mfma<1, 1><<<2 * CB / 32, 512, 0, stream>>>(
            xc, nullptr, wsH + px0f, wsH + ph0f, wsH + px0b, wsH + ph0b, bias + 0, bias + 512, yA);
        lstm_mfma<8, 0><<<2 * CB / 32, 512, 0, stream>>>(
            nullptr, yA, wsH + px1f, wsH + ph1f, wsH + px1b, wsH + ph1b, bias + 1024, bias + 1536, yB);
        lstm_mfma<8, 0><<<2 * CB / 32, 512, 0, stream>>>(
            nullptr, yB, wsH + px2f, wsH + ph2f, wsH + px2b, wsH + ph2b, bias + 2048, bias + 2560, yA);
        final_kernel<<<(CB + 3) / 4, 256, 0, stream>>>(yA, w_out, b_out, outc, CB);
    }
}